// Round 7
// baseline (256.353 us; speedup 1.0000x reference)
//
#include <hip/hip_runtime.h>

typedef __bf16 bf16;
typedef __bf16 bf16x8 __attribute__((ext_vector_type(8)));
typedef float  f32x4  __attribute__((ext_vector_type(4)));
typedef float  f32x16 __attribute__((ext_vector_type(16)));
typedef int    i32x4  __attribute__((ext_vector_type(4)));
typedef int    i32x16 __attribute__((ext_vector_type(16)));
typedef signed char i8;
typedef unsigned int u32;

#define OC_N   4096
#define IC_K   4096
#define TOKENS 4096
#define KC     256   // outlier K padded to 8x32

// ---------------------------------------------------------------------------
// Fused prep.  v6 change: wsgn i8 [4096][4096] (16 MB) replaced by 2-bit
// packed wsgn2 [64 chunks][4096 rows][16 B] (4 MB), chunk-major for
// coalesced gemm staging.  Code = sign&3 (0->0, +1->1, -1->3).  Quads
// (16 k = 4 B) are pre-swizzled within each 16-B chunk: slot s holds
// logical quad s ^ ((row>>3)&3)  (same involution the gemm read applies).
// All arithmetic/reductions BIT-IDENTICAL to v5 -> absmax must not move.
// ---------------------------------------------------------------------------
__global__ __launch_bounds__(256) void prep_kernel(
    const float* __restrict__ w, const float* __restrict__ x,
    const float* __restrict__ ow, const int* __restrict__ idx,
    i8* __restrict__ wsgn2, i8* __restrict__ xq,
    bf16* __restrict__ xo, bf16* __restrict__ wcorr,
    float* __restrict__ scale_arr, float* __restrict__ sx_arr, int n_out)
{
    __shared__ float red[8];
    const int row = blockIdx.x;
    const int t = threadIdx.x;
    const int lane = t & 63, wv = t >> 6;

    const float4* wr = (const float4*)(w + (size_t)row * IC_K);
    const float4* xr = (const float4*)(x + (size_t)row * IC_K);
    float4 v[4], u[4];
#pragma unroll
    for (int i = 0; i < 4; i++) v[i] = wr[i * 256 + t];
#pragma unroll
    for (int i = 0; i < 4; i++) u[i] = xr[i * 256 + t];

    float xg = 0.f, wg = 0.f, og = 0.f;
    if (t < n_out) {
        const int colg = idx[t];
        xg = x[(size_t)row * IC_K + colg];
        wg = w[(size_t)row * IC_K + colg];
        og = ow[(size_t)row * n_out + t];
    }

    float s = 0.f;
#pragma unroll
    for (int i = 0; i < 4; i++)
        s += v[i].x + v[i].y + v[i].z + v[i].w;
    for (int o = 32; o > 0; o >>= 1) s += __shfl_down(s, o, 64);
    if (lane == 0) red[wv] = s;
    __syncthreads();
    const float mean = (red[0] + red[1] + red[2] + red[3]) * (1.f / IC_K);

    float sa = 0.f;
#pragma unroll
    for (int i = 0; i < 4; i++) {
        sa += fabsf(v[i].x - mean) + fabsf(v[i].y - mean) +
              fabsf(v[i].z - mean) + fabsf(v[i].w - mean);
    }
    for (int o = 32; o > 0; o >>= 1) sa += __shfl_down(sa, o, 64);
    if (lane == 0) red[4 + wv] = sa;
    __syncthreads();
    const float scale = (red[4] + red[5] + red[6] + red[7]) * (1.f / IC_K);

    // ---- packed 2-bit sign store (replaces 16 MB i8 wsgn) ----
    {
        const int swzr = (row >> 3) & 3;
#pragma unroll
        for (int i = 0; i < 4; i++) {
            const float c0 = v[i].x - mean, c1 = v[i].y - mean;
            const float c2 = v[i].z - mean, c3 = v[i].w - mean;
            const int s0 = (c0 > 0.f) - (c0 < 0.f);
            const int s1 = (c1 > 0.f) - (c1 < 0.f);
            const int s2 = (c2 > 0.f) - (c2 < 0.f);
            const int s3 = (c3 > 0.f) - (c3 < 0.f);
            const unsigned pb = (unsigned)(s0 & 3) | ((unsigned)(s1 & 3) << 2) |
                                ((unsigned)(s2 & 3) << 4) | ((unsigned)(s3 & 3) << 6);
            const int cch  = i * 16 + (t >> 4);          // k-chunk 0..63
            const int slot = ((t >> 2) & 3) ^ swzr;       // pre-swizzled quad
            wsgn2[((size_t)cch * 4096 + row) * 16 + slot * 4 + (t & 3)] = (i8)pb;
        }
    }

    float mx = 0.f;
#pragma unroll
    for (int i = 0; i < 4; i++)
        mx = fmaxf(mx, fmaxf(fmaxf(fabsf(u[i].x), fabsf(u[i].y)),
                             fmaxf(fabsf(u[i].z), fabsf(u[i].w))));
    for (int o = 32; o > 0; o >>= 1) mx = fmaxf(mx, __shfl_down(mx, o, 64));
    if (lane == 0) red[wv] = mx;
    __syncthreads();
    const float maxv = fmaxf(fmaxf(red[0], red[1]), fmaxf(red[2], red[3]));
    const float inv = maxv > 0.f ? 127.f / maxv : 0.f;
    const float sxv = maxv > 0.f ? maxv * (1.f / 127.f) : 1.f;

    i8* xrow = xq + (size_t)row * IC_K;
#pragma unroll
    for (int i = 0; i < 4; i++) {
        char4 q;
        q.x = (i8)(int)rintf(u[i].x * inv);
        q.y = (i8)(int)rintf(u[i].y * inv);
        q.z = (i8)(int)rintf(u[i].z * inv);
        q.w = (i8)(int)rintf(u[i].w * inv);
        *(char4*)(xrow + (size_t)(i * 256 + t) * 4) = q;
    }
    if (t == 0) { scale_arr[row] = scale; sx_arr[row] = sxv; }

    if (t < n_out) {
        xo[(size_t)row * KC + t] = (bf16)xg;
        const float wc_ = wg - mean;
        const float sg = (wc_ > 0.f) ? 1.f : ((wc_ < 0.f) ? -1.f : 0.f);
        wcorr[(size_t)row * KC + t] = (bf16)(og - scale * sg);
    } else if (t < KC) {
        xo[(size_t)row * KC + t] = (bf16)0.f;
        wcorr[(size_t)row * KC + t] = (bf16)0.f;
    }
}

// ---------------------------------------------------------------------------
// GEMM v6: 256x256 tile, 8 waves, depth-5 ring, ONE barrier/phase (v5),
// + 2-BIT PACKED B.  Slot = A 16 KB + B 4 KB = 20 KB; ring 5x20480 = 100 KB.
// B staged by waves 0-3 only (1 gload16/wave covering 64 rows x 16 B);
// per-chunk loads: w0-3 = 3, w4-7 = 2 -> wave-uniform divergent waits:
// steady VMCNT(9)/(6); tails 9/6/3/0 and 6/4/2/0 (oldest-chunk arithmetic
// in v4 comments still applies, scaled by loads/chunk).
// B ds_read: b32 at r*16 + ((ks*2+kg) ^ ((r>>3)&3))*4 -- 32 lanes cover all
// 32 banks (r%8 x 4-slot XOR bijection), conflict-free; prep pre-applied
// the same involution on the store side (rule #21).
// Unpack 4 B -> 16 i8: SWAR 2-bit spread + v_perm_b32 LUT {0,1,3}->{0,1,FF}.
// Issued AFTER stage() so the lgkm wait on packed words overlaps staging.
// Correction loop: depth-3 view (3 x 32768 B) of the same LDS, 2-ahead,
// uniform 4 loads/chunk, VMCNT(4), tail 4/0.  WAR: stagec(c+2) writes slot
// (c+2)%3 != c%3; its previous readers (phase c-1) completed before the
// iter-c barrier.  Corr math/order identical to v5.
// ---------------------------------------------------------------------------
__device__ __forceinline__ void gload16(const void* g, void* l)
{
    __builtin_amdgcn_global_load_lds(
        (const __attribute__((address_space(1))) void*)g,
        (__attribute__((address_space(3))) void*)l, 16, 0, 0);
}

#define VMCNT(n) asm volatile("s_waitcnt vmcnt(" #n ")" ::: "memory")
#define SCHED0   __builtin_amdgcn_sched_barrier(0)
#define BAR      __builtin_amdgcn_s_barrier()

__global__ __launch_bounds__(512, 2) void gemm_kernel(
    const i8* __restrict__ A, const i8* __restrict__ Bp,
    const bf16* __restrict__ Axo, const bf16* __restrict__ Bwc,
    const float* __restrict__ sx, const float* __restrict__ scale,
    const float* __restrict__ bias, float* __restrict__ C)
{
    constexpr int K = IC_K, N = OC_N;
    __shared__ __align__(16) i8 ring[5 * 20480];   // 100 KB

    const int tid  = threadIdx.x;
    const int lane = tid & 63;
    const int wave = tid >> 6;
    const int wm = wave >> 2, wn = wave & 3;          // 2 (M) x 4 (N) waves
    const int m32 = lane & 31, kg = lane >> 5;

    // XCD-aware 4x8 rectangle per XCD (bijective; 256 blocks, 8 XCDs)
    const int bid = blockIdx.x;
    const int xcd = bid & 7, tix = bid >> 3;
    const int bm = (xcd >> 1) * 4 + (tix & 3);
    const int bn = (xcd & 1) * 8 + (tix >> 2);

    // ---- A staging map (unchanged): LDS quad Q -> (row, swizzled qk) ----
    const int Q0 = tid, Q1 = 512 + tid;
    const int r0 = Q0 >> 2, r1 = Q1 >> 2;
    const int q0 = (Q0 & 3) ^ ((r0 >> 1) & 3);
    const int q1 = (Q1 & 3) ^ ((r1 >> 1) & 3);
    const int d0 = Q0 * 16, d1 = Q1 * 16;

    const i8* gA0 = A + (size_t)(bm * 256 + r0) * K + q0 * 16;
    const i8* gA1 = A + (size_t)(bm * 256 + r1) * K + q1 * 16;
    // B packed: chunk-major [64][4096][16]; this block's panel rows
    const i8* gB2 = Bp + ((size_t)bn * 256 + tid) * 16;   // + c*65536

    auto stage = [&](int c) {
        i8* bs = ring + (c % 5) * 20480;
        const int ko = c * 64;
        gload16(gA0 + ko, bs + d0);
        gload16(gA1 + ko, bs + d1);
        if (wave < 4)
            gload16(gB2 + (size_t)c * 65536, bs + 16384 + tid * 16);
    };

    // ---- per-lane ds_read offsets ----
    int offA[4][2];
#pragma unroll
    for (int mi = 0; mi < 4; ++mi) {
        const int r = wm * 128 + mi * 32 + m32;
#pragma unroll
        for (int ks = 0; ks < 2; ++ks)
            offA[mi][ks] = r * 64 + ((ks * 2 + kg) ^ ((r >> 1) & 3)) * 16;
    }
    int offB[2][2], offB2[2][2];
#pragma unroll
    for (int ni = 0; ni < 2; ++ni) {
        const int r = wn * 64 + ni * 32 + m32;
#pragma unroll
        for (int ks = 0; ks < 2; ++ks) {
            offB[ni][ks]  = r * 64 + ((ks * 2 + kg) ^ ((r >> 1) & 3)) * 16; // bf16 corr
            offB2[ni][ks] = r * 16 + (((ks * 2 + kg) ^ ((r >> 3) & 3)) * 4); // packed i8
        }
    }

    const unsigned lutv = 0xFF000100u;   // sel 0->0x00, 1->0x01, 3->0xFF
    i32x16 acc[4][2] = {};

    auto loads_i8 = [&](int c, i32x4 (&af)[4][2], u32 (&pw)[2][2]) {
        const i8* sA = ring + (c % 5) * 20480;
        const i8* sB = sA + 16384;
#pragma unroll
        for (int mi = 0; mi < 4; ++mi)
#pragma unroll
            for (int ks = 0; ks < 2; ++ks)
                af[mi][ks] = *(const i32x4*)(sA + offA[mi][ks]);
#pragma unroll
        for (int ni = 0; ni < 2; ++ni)
#pragma unroll
            for (int ks = 0; ks < 2; ++ks)
                pw[ni][ks] = *(const u32*)(sB + offB2[ni][ks]);
    };
    auto mfma_i8 = [&](i32x4 (&af)[4][2], u32 (&pw)[2][2]) {
        i32x4 bfr[2][2];
#pragma unroll
        for (int ni = 0; ni < 2; ++ni)
#pragma unroll
            for (int ks = 0; ks < 2; ++ks) {
                const unsigned p = pw[ni][ks];
#pragma unroll
                for (int k = 0; k < 4; ++k) {
                    unsigned t2 = (p >> (8 * k)) & 0xFFu;
                    t2 = (t2 | (t2 << 12)) & 0x000F000Fu;
                    t2 = (t2 | (t2 << 6))  & 0x03030303u;
                    unsigned r;
                    asm("v_perm_b32 %0, %1, %1, %2" : "=v"(r) : "v"(lutv), "v"(t2));
                    bfr[ni][ks][k] = (int)r;
                }
            }
        __builtin_amdgcn_s_setprio(1);
#pragma unroll
        for (int ks = 0; ks < 2; ++ks)
#pragma unroll
            for (int mi = 0; mi < 4; ++mi)
#pragma unroll
                for (int ni = 0; ni < 2; ++ni)
                    acc[mi][ni] = __builtin_amdgcn_mfma_i32_32x32x32_i8(
                        af[mi][ks], bfr[ni][ks], acc[mi][ni], 0, 0, 0);
        __builtin_amdgcn_s_setprio(0);
    };

    // ---- main i8 loop: 64 chunks, depth 5, one barrier, reads-first ----
    stage(0); stage(1); stage(2); stage(3);
#pragma unroll 5
    for (int c = 0; c < 60; ++c) {
        if (wave < 4) { VMCNT(9); } else { VMCNT(6); }
        BAR; SCHED0;
        i32x4 af[4][2]; u32 pw[2][2];
        loads_i8(c, af, pw);
        SCHED0;
        stage(c + 4);
        SCHED0;
        mfma_i8(af, pw);
    }
    {
        i32x4 af[4][2]; u32 pw[2][2];
        if (wave < 4) { VMCNT(9); } else { VMCNT(6); }
        BAR; SCHED0; loads_i8(60, af, pw); SCHED0; mfma_i8(af, pw);
        if (wave < 4) { VMCNT(6); } else { VMCNT(4); }
        BAR; SCHED0; loads_i8(61, af, pw); SCHED0; mfma_i8(af, pw);
        if (wave < 4) { VMCNT(3); } else { VMCNT(2); }
        BAR; SCHED0; loads_i8(62, af, pw); SCHED0; mfma_i8(af, pw);
        VMCNT(0);
        BAR; SCHED0; loads_i8(63, af, pw); SCHED0; mfma_i8(af, pw);
    }

    // ---- i32 -> f32 scaling (32x32 C layout: row=(r&3)+8*(r>>2)+4*kg) ----
    const int rbase = bm * 256 + wm * 128 + 4 * kg;
    const int cbase = bn * 256 + wn * 64 + m32;
    float scl2[2], bv2[2];
#pragma unroll
    for (int ni = 0; ni < 2; ++ni) {
        scl2[ni] = scale[cbase + ni * 32];
        bv2[ni]  = bias[cbase + ni * 32];
    }
    f32x16 facc[4][2];
#pragma unroll
    for (int mi = 0; mi < 4; ++mi)
#pragma unroll
        for (int r = 0; r < 16; ++r) {
            const float sxv = sx[rbase + mi * 32 + (r & 3) + 8 * (r >> 2)];
#pragma unroll
            for (int ni = 0; ni < 2; ++ni)
                facc[mi][ni][r] = (float)acc[mi][ni][r] * sxv * scl2[ni];
        }
    // drain scalar-path loads so corr vmcnt counts are exact; publish
    asm volatile("s_waitcnt vmcnt(0)" ::: "memory");
    BAR;

    // ---- bf16 correction: 8 chunks of K=32, depth-3 32KB-slot ring ----
    const i8* cA0 = (const i8*)Axo + (size_t)(bm * 256 + r0) * (KC * 2) + q0 * 16;
    const i8* cA1 = (const i8*)Axo + (size_t)(bm * 256 + r1) * (KC * 2) + q1 * 16;
    const i8* cB0 = (const i8*)Bwc + (size_t)(bn * 256 + r0) * (KC * 2) + q0 * 16;
    const i8* cB1 = (const i8*)Bwc + (size_t)(bn * 256 + r1) * (KC * 2) + q1 * 16;
    auto stagec = [&](int c) {
        i8* bs = ring + (c % 3) * 32768;
        const int ko = c * 64;
        gload16(cA0 + ko, bs + d0);
        gload16(cA1 + ko, bs + d1);
        gload16(cB0 + ko, bs + 16384 + d0);
        gload16(cB1 + ko, bs + 16384 + d1);
    };
    auto reads_bf = [&](int c, bf16x8 (&af)[4][2], bf16x8 (&bfr)[2][2]) {
        const i8* sA = ring + (c % 3) * 32768;
        const i8* sB = sA + 16384;
#pragma unroll
        for (int mi = 0; mi < 4; ++mi)
#pragma unroll
            for (int ks = 0; ks < 2; ++ks)
                af[mi][ks] = *(const bf16x8*)(sA + offA[mi][ks]);
#pragma unroll
        for (int ni = 0; ni < 2; ++ni)
#pragma unroll
            for (int ks = 0; ks < 2; ++ks)
                bfr[ni][ks] = *(const bf16x8*)(sB + offB[ni][ks]);
    };
    auto mfma_bf = [&](bf16x8 (&af)[4][2], bf16x8 (&bfr)[2][2]) {
        __builtin_amdgcn_s_setprio(1);
#pragma unroll
        for (int ks = 0; ks < 2; ++ks)
#pragma unroll
            for (int mi = 0; mi < 4; ++mi)
#pragma unroll
                for (int ni = 0; ni < 2; ++ni)
                    facc[mi][ni] = __builtin_amdgcn_mfma_f32_32x32x16_bf16(
                        af[mi][ks], bfr[ni][ks], facc[mi][ni], 0, 0, 0);
        __builtin_amdgcn_s_setprio(0);
    };

    stagec(0); stagec(1);
#pragma unroll
    for (int c = 0; c < 6; ++c) {
        VMCNT(4); BAR; SCHED0;
        bf16x8 af[4][2], bfr[2][2];
        reads_bf(c, af, bfr);
        SCHED0;
        stagec(c + 2);
        SCHED0;
        mfma_bf(af, bfr);
    }
    {
        bf16x8 af[4][2], bfr[2][2];
        VMCNT(4); BAR; SCHED0; reads_bf(6, af, bfr); SCHED0; mfma_bf(af, bfr);
        VMCNT(0); BAR; SCHED0; reads_bf(7, af, bfr); SCHED0; mfma_bf(af, bfr);
    }

    // ---- epilogue: + bias, store ----
#pragma unroll
    for (int mi = 0; mi < 4; ++mi)
#pragma unroll
        for (int r = 0; r < 16; ++r) {
            const int row = rbase + mi * 32 + (r & 3) + 8 * (r >> 2);
#pragma unroll
            for (int ni = 0; ni < 2; ++ni)
                C[(size_t)row * N + cbase + ni * 32] = facc[mi][ni][r] + bv2[ni];
        }
}

// ---------------------------------------------------------------------------
extern "C" void kernel_launch(void* const* d_in, const int* in_sizes, int n_in,
                              void* d_out, int out_size, void* d_ws, size_t ws_size,
                              hipStream_t stream)
{
    const float* x    = (const float*)d_in[0];
    const float* w    = (const float*)d_in[1];
    const float* bias = (const float*)d_in[2];
    const float* ow   = (const float*)d_in[3];
    const int*   idx  = (const int*)d_in[4];
    const int    n_out = in_sizes[4];
    float* out = (float*)d_out;

    char* ws = (char*)d_ws;
    i8*    xq    = (i8*)ws;                                   // 16 MB
    i8*    wsgn2 = (i8*)(ws + (size_t)16 * 1024 * 1024);      // 4 MB packed
    bf16*  xo    = (bf16*)(ws + (size_t)20 * 1024 * 1024);    // 2 MB
    bf16*  wcorr = (bf16*)(ws + (size_t)22 * 1024 * 1024);    // 2 MB
    float* sx    = (float*)(ws + (size_t)24 * 1024 * 1024);   // 16 KB
    float* scl   = (float*)(ws + (size_t)24 * 1024 * 1024 + 16 * 1024); // 16 KB

    hipLaunchKernelGGL(prep_kernel, dim3(OC_N), dim3(256), 0, stream,
                       w, x, ow, idx, wsgn2, xq, xo, wcorr, scl, sx, n_out);
    hipLaunchKernelGGL(gemm_kernel, dim3(256), dim3(512), 0, stream,
                       xq, wsgn2, xo, wcorr, sx, scl, bias, out);
}

// Round 8
// 251.953 us; speedup vs baseline: 1.0175x; 1.0175x over previous
//
#include <hip/hip_runtime.h>

typedef __bf16 bf16;
typedef __bf16 bf16x8 __attribute__((ext_vector_type(8)));
typedef float  f32x4  __attribute__((ext_vector_type(4)));
typedef float  f32x16 __attribute__((ext_vector_type(16)));
typedef int    i32x4  __attribute__((ext_vector_type(4)));
typedef int    i32x16 __attribute__((ext_vector_type(16)));
typedef signed char i8;

#define OC_N   4096
#define IC_K   4096
#define TOKENS 4096
#define KC     256   // outlier K padded to 8x32

// ---------------------------------------------------------------------------
// Fused prep, one block per row r (TOKENS == OC_N == 4096).  (v5 version)
// ---------------------------------------------------------------------------
__global__ __launch_bounds__(256) void prep_kernel(
    const float* __restrict__ w, const float* __restrict__ x,
    const float* __restrict__ ow, const int* __restrict__ idx,
    i8* __restrict__ wsgn, i8* __restrict__ xq,
    bf16* __restrict__ xo, bf16* __restrict__ wcorr,
    float* __restrict__ scale_arr, float* __restrict__ sx_arr, int n_out)
{
    __shared__ float red[8];
    const int row = blockIdx.x;
    const int t = threadIdx.x;
    const int lane = t & 63, wv = t >> 6;

    const float4* wr = (const float4*)(w + (size_t)row * IC_K);
    const float4* xr = (const float4*)(x + (size_t)row * IC_K);
    float4 v[4], u[4];
#pragma unroll
    for (int i = 0; i < 4; i++) v[i] = wr[i * 256 + t];
#pragma unroll
    for (int i = 0; i < 4; i++) u[i] = xr[i * 256 + t];

    float xg = 0.f, wg = 0.f, og = 0.f;
    if (t < n_out) {
        const int colg = idx[t];
        xg = x[(size_t)row * IC_K + colg];
        wg = w[(size_t)row * IC_K + colg];
        og = ow[(size_t)row * n_out + t];
    }

    float s = 0.f;
#pragma unroll
    for (int i = 0; i < 4; i++)
        s += v[i].x + v[i].y + v[i].z + v[i].w;
    for (int o = 32; o > 0; o >>= 1) s += __shfl_down(s, o, 64);
    if (lane == 0) red[wv] = s;
    __syncthreads();
    const float mean = (red[0] + red[1] + red[2] + red[3]) * (1.f / IC_K);

    float sa = 0.f;
#pragma unroll
    for (int i = 0; i < 4; i++) {
        sa += fabsf(v[i].x - mean) + fabsf(v[i].y - mean) +
              fabsf(v[i].z - mean) + fabsf(v[i].w - mean);
    }
    for (int o = 32; o > 0; o >>= 1) sa += __shfl_down(sa, o, 64);
    if (lane == 0) red[4 + wv] = sa;
    __syncthreads();
    const float scale = (red[4] + red[5] + red[6] + red[7]) * (1.f / IC_K);

    i8* srow = wsgn + (size_t)row * IC_K;
#pragma unroll
    for (int i = 0; i < 4; i++) {
        float c[4] = { v[i].x - mean, v[i].y - mean, v[i].z - mean, v[i].w - mean };
        char4 q;
        q.x = (i8)((c[0] > 0.f) - (c[0] < 0.f));
        q.y = (i8)((c[1] > 0.f) - (c[1] < 0.f));
        q.z = (i8)((c[2] > 0.f) - (c[2] < 0.f));
        q.w = (i8)((c[3] > 0.f) - (c[3] < 0.f));
        *(char4*)(srow + (size_t)(i * 256 + t) * 4) = q;
    }

    float mx = 0.f;
#pragma unroll
    for (int i = 0; i < 4; i++)
        mx = fmaxf(mx, fmaxf(fmaxf(fabsf(u[i].x), fabsf(u[i].y)),
                             fmaxf(fabsf(u[i].z), fabsf(u[i].w))));
    for (int o = 32; o > 0; o >>= 1) mx = fmaxf(mx, __shfl_down(mx, o, 64));
    if (lane == 0) red[wv] = mx;
    __syncthreads();
    const float maxv = fmaxf(fmaxf(red[0], red[1]), fmaxf(red[2], red[3]));
    const float inv = maxv > 0.f ? 127.f / maxv : 0.f;
    const float sxv = maxv > 0.f ? maxv * (1.f / 127.f) : 1.f;

    i8* xrow = xq + (size_t)row * IC_K;
#pragma unroll
    for (int i = 0; i < 4; i++) {
        char4 q;
        q.x = (i8)(int)rintf(u[i].x * inv);
        q.y = (i8)(int)rintf(u[i].y * inv);
        q.z = (i8)(int)rintf(u[i].z * inv);
        q.w = (i8)(int)rintf(u[i].w * inv);
        *(char4*)(xrow + (size_t)(i * 256 + t) * 4) = q;
    }
    if (t == 0) { scale_arr[row] = scale; sx_arr[row] = sxv; }

    if (t < n_out) {
        xo[(size_t)row * KC + t] = (bf16)xg;
        const float wc_ = wg - mean;
        const float sg = (wc_ > 0.f) ? 1.f : ((wc_ < 0.f) ? -1.f : 0.f);
        wcorr[(size_t)row * KC + t] = (bf16)(og - scale * sg);
    } else if (t < KC) {
        xo[(size_t)row * KC + t] = (bf16)0.f;
        wcorr[(size_t)row * KC + t] = (bf16)0.f;
    }
}

// ---------------------------------------------------------------------------
// GEMM v7 == v5 (measured best: 83.0us, MfmaUtil 39%, FETCH 56MB).
// v6 (2-bit packed B) REVERTED: it cut FETCH 56->31MB and conflicts
// 7.08M->4.98M as modeled, but the SWAR+v_perm unpack added ~80 VALU
// ops/wave/phase on the MFMA critical path (VALUBusy 12->24%, MfmaUtil
// 39->33) -> gemm 83->98.5us.  Lesson: the binding constraint is
// post-barrier dependency latency + 2-wave/SIMD lockstep, NOT LDS/HBM
// volume; traffic cuts that add critical-path VALU are net losses.
// Structural box (why no further lever is taken):
//  - wall/phase ~2420cy vs pipes: LDS ~1790cy (74%), MFMA ~1170cy (48%)
//  - reg-double-buffer operands: +48 VGPR -> 8 waves x 304 > 2048/CU: no
//  - 2 blocks/CU: needs <=128 reg/wave; acc alone = 128 AGPR: no
//  - conflicts pinned at 7,077,888 across v2-v5 (read-pattern inherent)
// 256x256 tile, 8 waves (2Mx4N), depth-5 ring, ONE barrier per phase,
// reads-first body {VMCNT(12); BAR; reads(c); stage(c+4); MFMA(c)}.
// ---------------------------------------------------------------------------
__device__ __forceinline__ void gload16(const void* g, void* l)
{
    __builtin_amdgcn_global_load_lds(
        (const __attribute__((address_space(1))) void*)g,
        (__attribute__((address_space(3))) void*)l, 16, 0, 0);
}

#define VMCNT(n) asm volatile("s_waitcnt vmcnt(" #n ")" ::: "memory")
#define SCHED0   __builtin_amdgcn_sched_barrier(0)
#define BAR      __builtin_amdgcn_s_barrier()

__global__ __launch_bounds__(512, 2) void gemm_kernel(
    const i8* __restrict__ A, const i8* __restrict__ B,
    const bf16* __restrict__ Axo, const bf16* __restrict__ Bwc,
    const float* __restrict__ sx, const float* __restrict__ scale,
    const float* __restrict__ bias, float* __restrict__ C)
{
    constexpr int K = IC_K, N = OC_N;
    __shared__ __align__(16) i8 ring[5][2][16384];   // 160 KB (full pool)

    const int tid  = threadIdx.x;
    const int lane = tid & 63;
    const int wave = tid >> 6;
    const int wm = wave >> 2, wn = wave & 3;          // 2 (M) x 4 (N) waves
    const int m32 = lane & 31, kg = lane >> 5;

    // XCD-aware 4x8 rectangle per XCD (bijective; 256 blocks, 8 XCDs)
    const int bid = blockIdx.x;
    const int xcd = bid & 7, tix = bid >> 3;          // 32 tiles per XCD
    const int bm = (xcd >> 1) * 4 + (tix & 3);        // 16 values
    const int bn = (xcd & 1) * 8 + (tix >> 2);        // 16 values

    // ---- staging map: LDS quad Q = tid (+512) -> (row, swizzled qk) ----
    const int Q0 = tid, Q1 = 512 + tid;
    const int r0 = Q0 >> 2, r1 = Q1 >> 2;
    const int q0 = (Q0 & 3) ^ ((r0 >> 1) & 3);
    const int q1 = (Q1 & 3) ^ ((r1 >> 1) & 3);
    const int d0 = Q0 * 16, d1 = Q1 * 16;

    const i8* gA0 = A + (size_t)(bm * 256 + r0) * K + q0 * 16;
    const i8* gA1 = A + (size_t)(bm * 256 + r1) * K + q1 * 16;
    const i8* gB0 = B + (size_t)(bn * 256 + r0) * K + q0 * 16;
    const i8* gB1 = B + (size_t)(bn * 256 + r1) * K + q1 * 16;

    auto stage = [&](int c) {
        i8* bs = &ring[c % 5][0][0];
        const int ko = c * 64;
        gload16(gA0 + ko, bs + d0);
        gload16(gA1 + ko, bs + d1);
        gload16(gB0 + ko, bs + 16384 + d0);
        gload16(gB1 + ko, bs + 16384 + d1);
    };

    // ---- per-lane ds_read byte offsets (shared by i8 and bf16 loops) ----
    int offA[4][2], offB[2][2];
#pragma unroll
    for (int mi = 0; mi < 4; ++mi) {
        const int r = wm * 128 + mi * 32 + m32;
#pragma unroll
        for (int ks = 0; ks < 2; ++ks)
            offA[mi][ks] = r * 64 + ((ks * 2 + kg) ^ ((r >> 1) & 3)) * 16;
    }
#pragma unroll
    for (int ni = 0; ni < 2; ++ni) {
        const int r = wn * 64 + ni * 32 + m32;
#pragma unroll
        for (int ks = 0; ks < 2; ++ks)
            offB[ni][ks] = r * 64 + ((ks * 2 + kg) ^ ((r >> 1) & 3)) * 16;
    }

    i32x16 acc[4][2] = {};

    auto reads_i8 = [&](int c, i32x4 (&af)[4][2], i32x4 (&bfr)[2][2]) {
        const i8* sA = &ring[c % 5][0][0];
        const i8* sB = sA + 16384;
#pragma unroll
        for (int mi = 0; mi < 4; ++mi)
#pragma unroll
            for (int ks = 0; ks < 2; ++ks)
                af[mi][ks] = *(const i32x4*)(sA + offA[mi][ks]);
#pragma unroll
        for (int ni = 0; ni < 2; ++ni)
#pragma unroll
            for (int ks = 0; ks < 2; ++ks)
                bfr[ni][ks] = *(const i32x4*)(sB + offB[ni][ks]);
    };
    auto mfma_i8 = [&](i32x4 (&af)[4][2], i32x4 (&bfr)[2][2]) {
        __builtin_amdgcn_s_setprio(1);
#pragma unroll
        for (int ks = 0; ks < 2; ++ks)
#pragma unroll
            for (int mi = 0; mi < 4; ++mi)
#pragma unroll
                for (int ni = 0; ni < 2; ++ni)
                    acc[mi][ni] = __builtin_amdgcn_mfma_i32_32x32x32_i8(
                        af[mi][ks], bfr[ni][ks], acc[mi][ni], 0, 0, 0);
        __builtin_amdgcn_s_setprio(0);
    };

    // ---- main i8 loop: 64 chunks, depth 5, one barrier, reads-first ----
    stage(0); stage(1); stage(2); stage(3);
#pragma unroll 5
    for (int c = 0; c < 60; ++c) {
        VMCNT(12); BAR; SCHED0;
        i32x4 af[4][2], bfr[2][2];
        reads_i8(c, af, bfr);
        SCHED0;
        stage(c + 4);
        SCHED0;
        mfma_i8(af, bfr);
    }
    {
        i32x4 af[4][2], bfr[2][2];
        VMCNT(12); BAR; SCHED0; reads_i8(60, af, bfr); SCHED0; mfma_i8(af, bfr);
        VMCNT(8);  BAR; SCHED0; reads_i8(61, af, bfr); SCHED0; mfma_i8(af, bfr);
        VMCNT(4);  BAR; SCHED0; reads_i8(62, af, bfr); SCHED0; mfma_i8(af, bfr);
        VMCNT(0);  BAR; SCHED0; reads_i8(63, af, bfr); SCHED0; mfma_i8(af, bfr);
    }

    // ---- i32 -> f32 scaling (32x32 C layout: row=(r&3)+8*(r>>2)+4*kg) ----
    const int rbase = bm * 256 + wm * 128 + 4 * kg;
    const int cbase = bn * 256 + wn * 64 + m32;
    float scl2[2], bv2[2];
#pragma unroll
    for (int ni = 0; ni < 2; ++ni) {
        scl2[ni] = scale[cbase + ni * 32];
        bv2[ni]  = bias[cbase + ni * 32];
    }
    f32x16 facc[4][2];
#pragma unroll
    for (int mi = 0; mi < 4; ++mi)
#pragma unroll
        for (int r = 0; r < 16; ++r) {
            const float sxv = sx[rbase + mi * 32 + (r & 3) + 8 * (r >> 2)];
#pragma unroll
            for (int ni = 0; ni < 2; ++ni)
                facc[mi][ni][r] = (float)acc[mi][ni][r] * sxv * scl2[ni];
        }
    // drain sx/scale/bias loads (exact vmcnt counts for corr loop) and
    // barrier: all waves' i8-phase LDS reads are done before slot reuse.
    asm volatile("s_waitcnt vmcnt(0)" ::: "memory");
    BAR;

    // ---- bf16 correction: 8 chunks of K=32 over KC=256, same schedule ----
    const i8* cA0 = (const i8*)Axo + (size_t)(bm * 256 + r0) * (KC * 2) + q0 * 16;
    const i8* cA1 = (const i8*)Axo + (size_t)(bm * 256 + r1) * (KC * 2) + q1 * 16;
    const i8* cB0 = (const i8*)Bwc + (size_t)(bn * 256 + r0) * (KC * 2) + q0 * 16;
    const i8* cB1 = (const i8*)Bwc + (size_t)(bn * 256 + r1) * (KC * 2) + q1 * 16;
    auto stagec = [&](int c) {
        i8* bs = &ring[c % 5][0][0];
        const int ko = c * 64;
        gload16(cA0 + ko, bs + d0);
        gload16(cA1 + ko, bs + d1);
        gload16(cB0 + ko, bs + 16384 + d0);
        gload16(cB1 + ko, bs + 16384 + d1);
    };
    auto reads_bf = [&](int c, bf16x8 (&af)[4][2], bf16x8 (&bfr)[2][2]) {
        const i8* sA = &ring[c % 5][0][0];
        const i8* sB = sA + 16384;
#pragma unroll
        for (int mi = 0; mi < 4; ++mi)
#pragma unroll
            for (int ks = 0; ks < 2; ++ks)
                af[mi][ks] = *(const bf16x8*)(sA + offA[mi][ks]);
#pragma unroll
        for (int ni = 0; ni < 2; ++ni)
#pragma unroll
            for (int ks = 0; ks < 2; ++ks)
                bfr[ni][ks] = *(const bf16x8*)(sB + offB[ni][ks]);
    };
    auto mfma_bf = [&](bf16x8 (&af)[4][2], bf16x8 (&bfr)[2][2]) {
        __builtin_amdgcn_s_setprio(1);
#pragma unroll
        for (int ks = 0; ks < 2; ++ks)
#pragma unroll
            for (int mi = 0; mi < 4; ++mi)
#pragma unroll
                for (int ni = 0; ni < 2; ++ni)
                    facc[mi][ni] = __builtin_amdgcn_mfma_f32_32x32x16_bf16(
                        af[mi][ks], bfr[ni][ks], facc[mi][ni], 0, 0, 0);
        __builtin_amdgcn_s_setprio(0);
    };

    stagec(0); stagec(1); stagec(2);
#pragma unroll
    for (int c = 0; c < 5; ++c) {
        VMCNT(8); BAR; SCHED0;
        bf16x8 af[4][2], bfr[2][2];
        reads_bf(c, af, bfr);
        SCHED0;
        stagec(c + 3);
        SCHED0;
        mfma_bf(af, bfr);
    }
    {
        bf16x8 af[4][2], bfr[2][2];
        VMCNT(8); BAR; SCHED0; reads_bf(5, af, bfr); SCHED0; mfma_bf(af, bfr);
        VMCNT(4); BAR; SCHED0; reads_bf(6, af, bfr); SCHED0; mfma_bf(af, bfr);
        VMCNT(0); BAR; SCHED0; reads_bf(7, af, bfr); SCHED0; mfma_bf(af, bfr);
    }

    // ---- epilogue: + bias, store ----
#pragma unroll
    for (int mi = 0; mi < 4; ++mi)
#pragma unroll
        for (int r = 0; r < 16; ++r) {
            const int row = rbase + mi * 32 + (r & 3) + 8 * (r >> 2);
#pragma unroll
            for (int ni = 0; ni < 2; ++ni)
                C[(size_t)row * N + cbase + ni * 32] = facc[mi][ni][r] + bv2[ni];
        }
}

// ---------------------------------------------------------------------------
extern "C" void kernel_launch(void* const* d_in, const int* in_sizes, int n_in,
                              void* d_out, int out_size, void* d_ws, size_t ws_size,
                              hipStream_t stream)
{
    const float* x    = (const float*)d_in[0];
    const float* w    = (const float*)d_in[1];
    const float* bias = (const float*)d_in[2];
    const float* ow   = (const float*)d_in[3];
    const int*   idx  = (const int*)d_in[4];
    const int    n_out = in_sizes[4];
    float* out = (float*)d_out;

    char* ws = (char*)d_ws;
    i8*    xq    = (i8*)ws;                                   // 16 MB
    i8*    wsgn  = (i8*)(ws + (size_t)16 * 1024 * 1024);      // 16 MB
    bf16*  xo    = (bf16*)(ws + (size_t)32 * 1024 * 1024);    // 2 MB
    bf16*  wcorr = (bf16*)(ws + (size_t)34 * 1024 * 1024);    // 2 MB
    float* sx    = (float*)(ws + (size_t)36 * 1024 * 1024);   // 16 KB
    float* scl   = (float*)(ws + (size_t)36 * 1024 * 1024 + 16 * 1024); // 16 KB

    hipLaunchKernelGGL(prep_kernel, dim3(OC_N), dim3(256), 0, stream,
                       w, x, ow, idx, wsgn, xq, xo, wcorr, scl, sx, n_out);
    hipLaunchKernelGGL(gemm_kernel, dim3(256), dim3(512), 0, stream,
                       xq, wsgn, xo, wcorr, sx, scl, bias, out);
}